// Round 1
// baseline (3095.080 us; speedup 1.0000x reference)
//
#include <hip/hip_runtime.h>
#include <math.h>

#define NROWS 50000
#define DIN   3000
#define FH1   100
#define FH2   20
#define GH1   32
#define GH2   8
#define KCL   10
#define LAT   28
#define NEDGE 800000

static __device__ __forceinline__ float elu1(float v) {
  return v > 0.f ? v : expm1f(v);
}

#define BN_RS 0.99995000374968754f  /* 1/sqrt(1+1e-4) */

// ---------------- GEMM1: feat1 = ELU(BN(x @ W1 + b1)) ----------------
// BM=64, BN=128 (covers FH1=100), BK=24, block=256 (16x16), micro 4x(4+4)
__global__ __launch_bounds__(256) void k_gemm1(
    const float* __restrict__ x, const float* __restrict__ W,
    const float* __restrict__ b1, const float* __restrict__ g1, const float* __restrict__ bb1,
    float* __restrict__ out)
{
  __shared__ float As[24][64];
  __shared__ float Bs[24][128];
  const int tid = threadIdx.x;
  const int tx = tid & 15, ty = tid >> 4;
  const int rowBase = blockIdx.x * 64;

  float acc[4][8];
#pragma unroll
  for (int i = 0; i < 4; ++i)
#pragma unroll
    for (int j = 0; j < 8; ++j) acc[i][j] = 0.f;

  const int am  = tid >> 2;         // 0..63 (row within tile)
  const int akb = (tid & 3) * 6;    // 0,6,12,18
  const int bk  = tid >> 5;         // 0..7 (x3 -> 24 k rows)
  const int bn  = (tid & 31) * 4;   // 0..124
  const bool rowOK = (rowBase + am) < NROWS;
  const float* xrow = x + (size_t)(rowBase + am) * DIN;
  const bool bnOK = (bn < FH1);

  for (int k0 = 0; k0 < DIN; k0 += 24) {
    float2 a0 = make_float2(0.f, 0.f), a1 = a0, a2 = a0;
    if (rowOK) {
      a0 = *(const float2*)&xrow[k0 + akb + 0];
      a1 = *(const float2*)&xrow[k0 + akb + 2];
      a2 = *(const float2*)&xrow[k0 + akb + 4];
    }
    float4 bv0 = make_float4(0.f,0.f,0.f,0.f), bv1 = bv0, bv2 = bv0;
    if (bnOK) {
      bv0 = *(const float4*)&W[(size_t)(k0 + bk)      * FH1 + bn];
      bv1 = *(const float4*)&W[(size_t)(k0 + bk + 8)  * FH1 + bn];
      bv2 = *(const float4*)&W[(size_t)(k0 + bk + 16) * FH1 + bn];
    }
    __syncthreads();
    As[akb+0][am] = a0.x; As[akb+1][am] = a0.y;
    As[akb+2][am] = a1.x; As[akb+3][am] = a1.y;
    As[akb+4][am] = a2.x; As[akb+5][am] = a2.y;
    *(float4*)&Bs[bk     ][bn] = bv0;
    *(float4*)&Bs[bk +  8][bn] = bv1;
    *(float4*)&Bs[bk + 16][bn] = bv2;
    __syncthreads();

#pragma unroll
    for (int k = 0; k < 24; ++k) {
      const float4 a  = *(const float4*)&As[k][ty*4];
      const float4 p4 = *(const float4*)&Bs[k][tx*4];
      const float4 q4 = *(const float4*)&Bs[k][64 + tx*4];
#define FMA_ROW(i, AV) \
      acc[i][0] = fmaf(AV, p4.x, acc[i][0]); \
      acc[i][1] = fmaf(AV, p4.y, acc[i][1]); \
      acc[i][2] = fmaf(AV, p4.z, acc[i][2]); \
      acc[i][3] = fmaf(AV, p4.w, acc[i][3]); \
      acc[i][4] = fmaf(AV, q4.x, acc[i][4]); \
      acc[i][5] = fmaf(AV, q4.y, acc[i][5]); \
      acc[i][6] = fmaf(AV, q4.z, acc[i][6]); \
      acc[i][7] = fmaf(AV, q4.w, acc[i][7]);
      FMA_ROW(0, a.x)
      FMA_ROW(1, a.y)
      FMA_ROW(2, a.z)
      FMA_ROW(3, a.w)
#undef FMA_ROW
    }
  }

  // epilogue: bias -> BN(eval) -> ELU
#pragma unroll
  for (int i = 0; i < 4; ++i) {
    const int row = rowBase + ty*4 + i;
    if (row >= NROWS) continue;
#pragma unroll
    for (int j = 0; j < 8; ++j) {
      const int col = (j < 4) ? (tx*4 + j) : (64 + tx*4 + (j - 4));
      if (col < FH1) {
        float v = (acc[i][j] + b1[col]) * (g1[col] * BN_RS) + bb1[col];
        out[(size_t)row * FH1 + col] = elu1(v);
      }
    }
  }
}

// ---------------- feat_x = ELU(BN(feat1 @ W2 + b2)); t1 = feat_x @ gc1_W ----------------
__global__ __launch_bounds__(256) void k_enc2_gc1(
    const float* __restrict__ feat1, const float* __restrict__ W2, const float* __restrict__ b2,
    const float* __restrict__ g2, const float* __restrict__ bb2,
    const float* __restrict__ gc1W,
    float* __restrict__ fx_out, float* __restrict__ t1_out)
{
  const int row = blockIdx.x * blockDim.x + threadIdx.x;
  if (row >= NROWS) return;
  float f1[FH1];
  const float4* fr = (const float4*)(feat1 + (size_t)row * FH1);
#pragma unroll
  for (int i = 0; i < FH1/4; ++i) ((float4*)f1)[i] = fr[i];

  float fx[FH2];
#pragma unroll
  for (int j = 0; j < FH2; ++j) fx[j] = b2[j];
#pragma unroll
  for (int k = 0; k < FH1; ++k) {
    const float f = f1[k];
#pragma unroll
    for (int j = 0; j < FH2; ++j) fx[j] = fmaf(f, W2[k*FH2 + j], fx[j]);
  }
#pragma unroll
  for (int j = 0; j < FH2; ++j) fx[j] = elu1(fx[j] * (g2[j] * BN_RS) + bb2[j]);

  float4* fo = (float4*)(fx_out + (size_t)row * FH2);
#pragma unroll
  for (int i = 0; i < FH2/4; ++i) fo[i] = ((float4*)fx)[i];

  float t[GH1];
#pragma unroll
  for (int j = 0; j < GH1; ++j) t[j] = 0.f;
#pragma unroll
  for (int k = 0; k < FH2; ++k) {
    const float f = fx[k];
#pragma unroll
    for (int j = 0; j < GH1; ++j) t[j] = fmaf(f, gc1W[k*GH1 + j], t[j]);
  }
  float4* to = (float4*)(t1_out + (size_t)row * GH1);
#pragma unroll
  for (int i = 0; i < GH1/4; ++i) to[i] = ((float4*)t)[i];
}

// ---------------- zero fill ----------------
__global__ void k_zero(float* __restrict__ p, int n) {
  for (int i = blockIdx.x * blockDim.x + threadIdx.x; i < n; i += gridDim.x * blockDim.x)
    p[i] = 0.f;
}

// ---------------- spmm1: h1 += val * t1[col]  (scatter to row), 8 threads/edge ----------------
__global__ void k_spmm1(const float* __restrict__ vals, const int* __restrict__ er,
                        const int* __restrict__ ec, const float* __restrict__ t1,
                        float* __restrict__ h1)
{
  const int idx = blockIdx.x * blockDim.x + threadIdx.x;
  const int e = idx >> 3, p = idx & 7;
  if (e >= NEDGE) return;
  const int r = er[e], c = ec[e];
  const float v = vals[e];
  const float4 tv = *(const float4*)&t1[(size_t)c * GH1 + p * 4];
  float* dst = &h1[(size_t)r * GH1 + p * 4];
  unsafeAtomicAdd(dst + 0, v * tv.x);
  unsafeAtomicAdd(dst + 1, v * tv.y);
  unsafeAtomicAdd(dst + 2, v * tv.z);
  unsafeAtomicAdd(dst + 3, v * tv.w);
}

// ---------------- mu_pre/lv_pre = relu(h1) @ gc2W / gc3W ----------------
__global__ __launch_bounds__(256) void k_h1gc(
    const float* __restrict__ h1, const float* __restrict__ gc2W, const float* __restrict__ gc3W,
    float* __restrict__ mp, float* __restrict__ lp)
{
  const int row = blockIdx.x * blockDim.x + threadIdx.x;
  if (row >= NROWS) return;
  float h[GH1];
  const float4* hr = (const float4*)(h1 + (size_t)row * GH1);
#pragma unroll
  for (int i = 0; i < GH1/4; ++i) ((float4*)h)[i] = hr[i];
#pragma unroll
  for (int k = 0; k < GH1; ++k) h[k] = fmaxf(h[k], 0.f);

  float m[GH2], l[GH2];
#pragma unroll
  for (int j = 0; j < GH2; ++j) { m[j] = 0.f; l[j] = 0.f; }
#pragma unroll
  for (int k = 0; k < GH1; ++k) {
    const float hv = h[k];
#pragma unroll
    for (int j = 0; j < GH2; ++j) {
      m[j] = fmaf(hv, gc2W[k*GH2 + j], m[j]);
      l[j] = fmaf(hv, gc3W[k*GH2 + j], l[j]);
    }
  }
  float4* mo = (float4*)(mp + (size_t)row * GH2);
  float4* lo = (float4*)(lp + (size_t)row * GH2);
  mo[0] = ((float4*)m)[0]; mo[1] = ((float4*)m)[1];
  lo[0] = ((float4*)l)[0]; lo[1] = ((float4*)l)[1];
}

// ---------------- spmm2: mu += val*mp[col]; lv += val*lp[col]; 4 threads/edge ----------------
__global__ void k_spmm2(const float* __restrict__ vals, const int* __restrict__ er,
                        const int* __restrict__ ec, const float* __restrict__ mp,
                        const float* __restrict__ lp,
                        float* __restrict__ mu, float* __restrict__ lv)
{
  const int idx = blockIdx.x * blockDim.x + threadIdx.x;
  const int e = idx >> 2, p = idx & 3;
  if (e >= NEDGE) return;
  const int r = er[e], c = ec[e];
  const float v = vals[e];
  const float* src = (p < 2) ? mp : lp;
  float* dstb = (p < 2) ? mu : lv;
  const int off = (p & 1) * 4;
  const float4 sv = *(const float4*)&src[(size_t)c * GH2 + off];
  float* dst = &dstb[(size_t)r * GH2 + off];
  unsafeAtomicAdd(dst + 0, v * sv.x);
  unsafeAtomicAdd(dst + 1, v * sv.y);
  unsafeAtomicAdd(dst + 2, v * sv.z);
  unsafeAtomicAdd(dst + 3, v * sv.w);
}

// ---------------- z = [feat_x | mu]; gnn_z = mu; q = student-t ----------------
__global__ __launch_bounds__(256) void k_zq(
    const float* __restrict__ fx, const float* __restrict__ mu, const float* __restrict__ clus,
    float* __restrict__ z_o, float* __restrict__ gz_o, float* __restrict__ q_o)
{
  const int row = blockIdx.x * blockDim.x + threadIdx.x;
  if (row >= NROWS) return;
  float z[LAT];
  const float4* f4 = (const float4*)(fx + (size_t)row * FH2);
#pragma unroll
  for (int i = 0; i < FH2/4; ++i) ((float4*)z)[i] = f4[i];
  const float4* m4 = (const float4*)(mu + (size_t)row * GH2);
  ((float4*)z)[5] = m4[0];
  ((float4*)z)[6] = m4[1];

  float4* zo = (float4*)(z_o + (size_t)row * LAT);
#pragma unroll
  for (int i = 0; i < LAT/4; ++i) zo[i] = ((float4*)z)[i];
  float4* go = (float4*)(gz_o + (size_t)row * GH2);
  go[0] = m4[0]; go[1] = m4[1];

  float q[KCL];
  float ssum = 0.f;
#pragma unroll
  for (int j = 0; j < KCL; ++j) {
    float d = 0.f;
#pragma unroll
    for (int k = 0; k < LAT; ++k) {
      const float df = z[k] - clus[j*LAT + k];
      d = fmaf(df, df, d);
    }
    q[j] = 1.f / (1.f + d);
    ssum += q[j];
  }
  const float inv = 1.f / ssum;
#pragma unroll
  for (int j = 0; j < KCL; ++j) q[j] *= inv;
  float2* qo = (float2*)(q_o + (size_t)row * KCL);
#pragma unroll
  for (int i = 0; i < KCL/2; ++i) qo[i] = ((float2*)q)[i];
}

// ---------------- decoder: de_feat = ELU(BN(z @ dec_W + dec_b)), 60-col chunks ----------------
__global__ __launch_bounds__(256) void k_dec(
    const float* __restrict__ z, const float* __restrict__ W, const float* __restrict__ db,
    const float* __restrict__ g3, const float* __restrict__ bb3, float* __restrict__ out)
{
  const int row = blockIdx.x * 256 + threadIdx.x;
  const int c0 = blockIdx.y * 60;
  const bool ok = row < NROWS;
  float zr[LAT];
#pragma unroll
  for (int i = 0; i < LAT; ++i) zr[i] = 0.f;
  if (ok) {
    const float4* z4 = (const float4*)(z + (size_t)row * LAT);
#pragma unroll
    for (int i = 0; i < LAT/4; ++i) ((float4*)zr)[i] = z4[i];
  }
  float acc[60];
#pragma unroll
  for (int c = 0; c < 60; ++c) acc[c] = 0.f;
#pragma unroll
  for (int k = 0; k < LAT; ++k) {
    const float* wr = W + (size_t)k * DIN + c0;  // block-uniform -> scalar loads
    const float zk = zr[k];
#pragma unroll
    for (int c = 0; c < 60; ++c) acc[c] = fmaf(zk, wr[c], acc[c]);
  }
  if (!ok) return;
  float val[60];
#pragma unroll
  for (int c = 0; c < 60; ++c) {
    const int col = c0 + c;
    val[c] = elu1((acc[c] + db[col]) * (g3[col] * BN_RS) + bb3[col]);
  }
  float4* o4 = (float4*)(out + (size_t)row * DIN + c0);
#pragma unroll
  for (int i = 0; i < 15; ++i) o4[i] = ((float4*)val)[i];
}

extern "C" void kernel_launch(void* const* d_in, const int* in_sizes, int n_in,
                              void* d_out, int out_size, void* d_ws, size_t ws_size,
                              hipStream_t stream) {
  const float* x    = (const float*)d_in[0];
  const float* vals = (const float*)d_in[1];
  const float* W1   = (const float*)d_in[2];
  const float* b1   = (const float*)d_in[3];
  const float* g1   = (const float*)d_in[4];
  const float* bb1  = (const float*)d_in[5];
  const float* W2   = (const float*)d_in[6];
  const float* b2   = (const float*)d_in[7];
  const float* g2   = (const float*)d_in[8];
  const float* bb2  = (const float*)d_in[9];
  const float* gc1W = (const float*)d_in[10];
  const float* gc2W = (const float*)d_in[11];
  const float* gc3W = (const float*)d_in[12];
  const float* dW   = (const float*)d_in[13];
  const float* db   = (const float*)d_in[14];
  const float* g3   = (const float*)d_in[15];
  const float* bb3  = (const float*)d_in[16];
  const float* clus = (const float*)d_in[17];
  const int* erow   = (const int*)d_in[18];
  const int* ecol   = (const int*)d_in[19];

  float* out  = (float*)d_out;
  float* z_o  = out;
  float* mu_o = out + (size_t)NROWS * 28;
  float* lv_o = out + (size_t)NROWS * 36;
  float* de_o = out + (size_t)NROWS * 44;
  float* q_o  = out + (size_t)NROWS * 3044;
  float* fx_o = out + (size_t)NROWS * 3054;
  float* gz_o = out + (size_t)NROWS * 3074;

  // scratch lives inside the de_feat region (written last, fully overwritten)
  float* feat1 = de_o;
  float* t1    = de_o + (size_t)NROWS * 100;
  float* h1    = de_o + (size_t)NROWS * 132;
  float* mp    = de_o + (size_t)NROWS * 164;
  float* lp    = de_o + (size_t)NROWS * 172;

  k_gemm1<<<dim3((NROWS + 63) / 64), 256, 0, stream>>>(x, W1, b1, g1, bb1, feat1);
  k_enc2_gc1<<<dim3((NROWS + 255) / 256), 256, 0, stream>>>(feat1, W2, b2, g2, bb2, gc1W, fx_o, t1);
  k_zero<<<dim3(512), 256, 0, stream>>>(h1, NROWS * 48);          // h1 + mp + lp (contiguous)
  k_zero<<<dim3(128), 256, 0, stream>>>(mu_o, NROWS * 16);        // mu + logvar (contiguous)
  k_spmm1<<<dim3(NEDGE * 8 / 256), 256, 0, stream>>>(vals, erow, ecol, t1, h1);
  k_h1gc<<<dim3((NROWS + 255) / 256), 256, 0, stream>>>(h1, gc2W, gc3W, mp, lp);
  k_spmm2<<<dim3(NEDGE * 4 / 256), 256, 0, stream>>>(vals, erow, ecol, mp, lp, mu_o, lv_o);
  k_zq<<<dim3((NROWS + 255) / 256), 256, 0, stream>>>(fx_o, mu_o, clus, z_o, gz_o, q_o);
  k_dec<<<dim3((NROWS + 255) / 256, 50), 256, 0, stream>>>(z_o, dW, db, g3, bb3, de_o);
}

// Round 2
// 1504.708 us; speedup vs baseline: 2.0569x; 2.0569x over previous
//
#include <hip/hip_runtime.h>
#include <math.h>

#define NROWS 50000
#define DIN   3000
#define FH1   100
#define FH2   20
#define GH1   32
#define GH2   8
#define KCL   10
#define LAT   28
#define NEDGE 800000

static __device__ __forceinline__ float elu1(float v) {
  return v > 0.f ? v : (__expf(v) - 1.f);
}

#define BN_RS 0.99995000374968754f  /* 1/sqrt(1+1e-4) */

// ---------------- GEMM1: feat1 = ELU(BN(x @ W1 + b1)) ----------------
// BM=64, BN=128 (covers FH1=100), BK=24, block=256 (16x16), micro 4x(4+4)
__global__ __launch_bounds__(256) void k_gemm1(
    const float* __restrict__ x, const float* __restrict__ W,
    const float* __restrict__ b1, const float* __restrict__ g1, const float* __restrict__ bb1,
    float* __restrict__ out)
{
  __shared__ float As[24][64];
  __shared__ float Bs[24][128];
  const int tid = threadIdx.x;
  const int tx = tid & 15, ty = tid >> 4;
  const int rowBase = blockIdx.x * 64;

  float acc[4][8];
#pragma unroll
  for (int i = 0; i < 4; ++i)
#pragma unroll
    for (int j = 0; j < 8; ++j) acc[i][j] = 0.f;

  const int am  = tid >> 2;         // 0..63 (row within tile)
  const int akb = (tid & 3) * 6;    // 0,6,12,18
  const int bk  = tid >> 5;         // 0..7 (x3 -> 24 k rows)
  const int bn  = (tid & 31) * 4;   // 0..124
  const bool rowOK = (rowBase + am) < NROWS;
  const float* xrow = x + (size_t)(rowBase + am) * DIN;
  const bool bnOK = (bn < FH1);

  for (int k0 = 0; k0 < DIN; k0 += 24) {
    float2 a0 = make_float2(0.f, 0.f), a1 = a0, a2 = a0;
    if (rowOK) {
      a0 = *(const float2*)&xrow[k0 + akb + 0];
      a1 = *(const float2*)&xrow[k0 + akb + 2];
      a2 = *(const float2*)&xrow[k0 + akb + 4];
    }
    float4 bv0 = make_float4(0.f,0.f,0.f,0.f), bv1 = bv0, bv2 = bv0;
    if (bnOK) {
      bv0 = *(const float4*)&W[(size_t)(k0 + bk)      * FH1 + bn];
      bv1 = *(const float4*)&W[(size_t)(k0 + bk + 8)  * FH1 + bn];
      bv2 = *(const float4*)&W[(size_t)(k0 + bk + 16) * FH1 + bn];
    }
    __syncthreads();
    As[akb+0][am] = a0.x; As[akb+1][am] = a0.y;
    As[akb+2][am] = a1.x; As[akb+3][am] = a1.y;
    As[akb+4][am] = a2.x; As[akb+5][am] = a2.y;
    *(float4*)&Bs[bk     ][bn] = bv0;
    *(float4*)&Bs[bk +  8][bn] = bv1;
    *(float4*)&Bs[bk + 16][bn] = bv2;
    __syncthreads();

#pragma unroll
    for (int k = 0; k < 24; ++k) {
      const float4 a  = *(const float4*)&As[k][ty*4];
      const float4 p4 = *(const float4*)&Bs[k][tx*4];
      const float4 q4 = *(const float4*)&Bs[k][64 + tx*4];
#define FMA_ROW(i, AV) \
      acc[i][0] = fmaf(AV, p4.x, acc[i][0]); \
      acc[i][1] = fmaf(AV, p4.y, acc[i][1]); \
      acc[i][2] = fmaf(AV, p4.z, acc[i][2]); \
      acc[i][3] = fmaf(AV, p4.w, acc[i][3]); \
      acc[i][4] = fmaf(AV, q4.x, acc[i][4]); \
      acc[i][5] = fmaf(AV, q4.y, acc[i][5]); \
      acc[i][6] = fmaf(AV, q4.z, acc[i][6]); \
      acc[i][7] = fmaf(AV, q4.w, acc[i][7]);
      FMA_ROW(0, a.x)
      FMA_ROW(1, a.y)
      FMA_ROW(2, a.z)
      FMA_ROW(3, a.w)
#undef FMA_ROW
    }
  }

  // epilogue: bias -> BN(eval) -> ELU
#pragma unroll
  for (int i = 0; i < 4; ++i) {
    const int row = rowBase + ty*4 + i;
    if (row >= NROWS) continue;
#pragma unroll
    for (int j = 0; j < 8; ++j) {
      const int col = (j < 4) ? (tx*4 + j) : (64 + tx*4 + (j - 4));
      if (col < FH1) {
        float v = (acc[i][j] + b1[col]) * (g1[col] * BN_RS) + bb1[col];
        out[(size_t)row * FH1 + col] = elu1(v);
      }
    }
  }
}

// ---------------- feat_x = ELU(BN(feat1 @ W2 + b2)); t1 = feat_x @ gc1_W ----------------
__global__ __launch_bounds__(256) void k_enc2_gc1(
    const float* __restrict__ feat1, const float* __restrict__ W2, const float* __restrict__ b2,
    const float* __restrict__ g2, const float* __restrict__ bb2,
    const float* __restrict__ gc1W,
    float* __restrict__ fx_out, float* __restrict__ t1_out)
{
  const int row = blockIdx.x * blockDim.x + threadIdx.x;
  if (row >= NROWS) return;
  float f1[FH1];
  const float4* fr = (const float4*)(feat1 + (size_t)row * FH1);
#pragma unroll
  for (int i = 0; i < FH1/4; ++i) ((float4*)f1)[i] = fr[i];

  float fx[FH2];
#pragma unroll
  for (int j = 0; j < FH2; ++j) fx[j] = b2[j];
#pragma unroll
  for (int k = 0; k < FH1; ++k) {
    const float f = f1[k];
#pragma unroll
    for (int j = 0; j < FH2; ++j) fx[j] = fmaf(f, W2[k*FH2 + j], fx[j]);
  }
#pragma unroll
  for (int j = 0; j < FH2; ++j) fx[j] = elu1(fx[j] * (g2[j] * BN_RS) + bb2[j]);

  float4* fo = (float4*)(fx_out + (size_t)row * FH2);
#pragma unroll
  for (int i = 0; i < FH2/4; ++i) fo[i] = ((float4*)fx)[i];

  float t[GH1];
#pragma unroll
  for (int j = 0; j < GH1; ++j) t[j] = 0.f;
#pragma unroll
  for (int k = 0; k < FH2; ++k) {
    const float f = fx[k];
#pragma unroll
    for (int j = 0; j < GH1; ++j) t[j] = fmaf(f, gc1W[k*GH1 + j], t[j]);
  }
  float4* to = (float4*)(t1_out + (size_t)row * GH1);
#pragma unroll
  for (int i = 0; i < GH1/4; ++i) to[i] = ((float4*)t)[i];
}

// ---------------- zero fill ----------------
__global__ void k_zero(float* __restrict__ p, int n) {
  for (int i = blockIdx.x * blockDim.x + threadIdx.x; i < n; i += gridDim.x * blockDim.x)
    p[i] = 0.f;
}

// ---------------- spmm1: h1 += val * t1[col]  (scatter to row), 8 threads/edge ----------------
__global__ void k_spmm1(const float* __restrict__ vals, const int* __restrict__ er,
                        const int* __restrict__ ec, const float* __restrict__ t1,
                        float* __restrict__ h1)
{
  const int idx = blockIdx.x * blockDim.x + threadIdx.x;
  const int e = idx >> 3, p = idx & 7;
  if (e >= NEDGE) return;
  const int r = er[e], c = ec[e];
  const float v = vals[e];
  const float4 tv = *(const float4*)&t1[(size_t)c * GH1 + p * 4];
  float* dst = &h1[(size_t)r * GH1 + p * 4];
  unsafeAtomicAdd(dst + 0, v * tv.x);
  unsafeAtomicAdd(dst + 1, v * tv.y);
  unsafeAtomicAdd(dst + 2, v * tv.z);
  unsafeAtomicAdd(dst + 3, v * tv.w);
}

// ---------------- mu_pre/lv_pre = relu(h1) @ gc2W / gc3W ----------------
__global__ __launch_bounds__(256) void k_h1gc(
    const float* __restrict__ h1, const float* __restrict__ gc2W, const float* __restrict__ gc3W,
    float* __restrict__ mp, float* __restrict__ lp)
{
  const int row = blockIdx.x * blockDim.x + threadIdx.x;
  if (row >= NROWS) return;
  float h[GH1];
  const float4* hr = (const float4*)(h1 + (size_t)row * GH1);
#pragma unroll
  for (int i = 0; i < GH1/4; ++i) ((float4*)h)[i] = hr[i];
#pragma unroll
  for (int k = 0; k < GH1; ++k) h[k] = fmaxf(h[k], 0.f);

  float m[GH2], l[GH2];
#pragma unroll
  for (int j = 0; j < GH2; ++j) { m[j] = 0.f; l[j] = 0.f; }
#pragma unroll
  for (int k = 0; k < GH1; ++k) {
    const float hv = h[k];
#pragma unroll
    for (int j = 0; j < GH2; ++j) {
      m[j] = fmaf(hv, gc2W[k*GH2 + j], m[j]);
      l[j] = fmaf(hv, gc3W[k*GH2 + j], l[j]);
    }
  }
  float4* mo = (float4*)(mp + (size_t)row * GH2);
  float4* lo = (float4*)(lp + (size_t)row * GH2);
  mo[0] = ((float4*)m)[0]; mo[1] = ((float4*)m)[1];
  lo[0] = ((float4*)l)[0]; lo[1] = ((float4*)l)[1];
}

// ---------------- spmm2: mu += val*mp[col]; lv += val*lp[col]; 4 threads/edge ----------------
__global__ void k_spmm2(const float* __restrict__ vals, const int* __restrict__ er,
                        const int* __restrict__ ec, const float* __restrict__ mp,
                        const float* __restrict__ lp,
                        float* __restrict__ mu, float* __restrict__ lv)
{
  const int idx = blockIdx.x * blockDim.x + threadIdx.x;
  const int e = idx >> 2, p = idx & 3;
  if (e >= NEDGE) return;
  const int r = er[e], c = ec[e];
  const float v = vals[e];
  const float* src = (p < 2) ? mp : lp;
  float* dstb = (p < 2) ? mu : lv;
  const int off = (p & 1) * 4;
  const float4 sv = *(const float4*)&src[(size_t)c * GH2 + off];
  float* dst = &dstb[(size_t)r * GH2 + off];
  unsafeAtomicAdd(dst + 0, v * sv.x);
  unsafeAtomicAdd(dst + 1, v * sv.y);
  unsafeAtomicAdd(dst + 2, v * sv.z);
  unsafeAtomicAdd(dst + 3, v * sv.w);
}

// ---------------- z = [feat_x | mu]; gnn_z = mu; q = student-t ----------------
__global__ __launch_bounds__(256) void k_zq(
    const float* __restrict__ fx, const float* __restrict__ mu, const float* __restrict__ clus,
    float* __restrict__ z_o, float* __restrict__ gz_o, float* __restrict__ q_o)
{
  const int row = blockIdx.x * blockDim.x + threadIdx.x;
  if (row >= NROWS) return;
  float z[LAT];
  const float4* f4 = (const float4*)(fx + (size_t)row * FH2);
#pragma unroll
  for (int i = 0; i < FH2/4; ++i) ((float4*)z)[i] = f4[i];
  const float4* m4 = (const float4*)(mu + (size_t)row * GH2);
  ((float4*)z)[5] = m4[0];
  ((float4*)z)[6] = m4[1];

  float4* zo = (float4*)(z_o + (size_t)row * LAT);
#pragma unroll
  for (int i = 0; i < LAT/4; ++i) zo[i] = ((float4*)z)[i];
  float4* go = (float4*)(gz_o + (size_t)row * GH2);
  go[0] = m4[0]; go[1] = m4[1];

  float q[KCL];
  float ssum = 0.f;
#pragma unroll
  for (int j = 0; j < KCL; ++j) {
    float d = 0.f;
#pragma unroll
    for (int k = 0; k < LAT; ++k) {
      const float df = z[k] - clus[j*LAT + k];
      d = fmaf(df, df, d);
    }
    q[j] = 1.f / (1.f + d);
    ssum += q[j];
  }
  const float inv = 1.f / ssum;
#pragma unroll
  for (int j = 0; j < KCL; ++j) q[j] *= inv;
  float2* qo = (float2*)(q_o + (size_t)row * KCL);
#pragma unroll
  for (int i = 0; i < KCL/2; ++i) qo[i] = ((float2*)q)[i];
}

// ---------------- decoder v2: 16 rows x 256 cols per block, LDS-staged ----------------
// de_feat = ELU(BN(z @ dec_W + dec_b)); K=28 fits in one stage, one barrier.
// Thread micro-tile: 4 rows x 4 cols in registers (acc[4][4]); coalesced float4 stores.
__global__ __launch_bounds__(256) void k_dec(
    const float* __restrict__ z, const float* __restrict__ W, const float* __restrict__ db,
    const float* __restrict__ g3, const float* __restrict__ bb3, float* __restrict__ out)
{
  __shared__ float Ws[LAT][256];   // 28 KB
  __shared__ float zs[16 * LAT];   // 1.75 KB

  const int tid = threadIdx.x;
  const int c0  = blockIdx.x * 256;       // col base (12 chunks, last partial)
  const int r0  = blockIdx.y * 16;        // row base (3125 chunks, exact)

  // stage W tile [28][256] cooperatively: 1792 float4s / 256 thr = 7 each, coalesced
#pragma unroll
  for (int rep = 0; rep < 7; ++rep) {
    const int f4 = rep * 256 + tid;       // 0..1791
    const int k  = f4 >> 6;               // 0..27
    const int cg = (f4 & 63) * 4;         // 0..252
    float4 v = make_float4(0.f, 0.f, 0.f, 0.f);
    if (c0 + cg < DIN) v = *(const float4*)&W[(size_t)k * DIN + c0 + cg];
    *(float4*)&Ws[k][cg] = v;
  }
  // stage z slice [16 rows x 28] = 448 floats contiguous
  if (tid < 112) {
    *(float4*)&zs[tid * 4] = *(const float4*)&z[(size_t)r0 * LAT + tid * 4];
  }
  __syncthreads();

  const int w    = tid >> 6;   // wave 0..3 -> rows r0 + w*4 .. +3
  const int lane = tid & 63;
  const int cl   = lane * 4;   // 0..252
  const int rloc = w * 4;

  float acc[4][4];
#pragma unroll
  for (int i = 0; i < 4; ++i)
#pragma unroll
    for (int j = 0; j < 4; ++j) acc[i][j] = 0.f;

#pragma unroll
  for (int k4 = 0; k4 < 7; ++k4) {
    float zq[4][4];
#pragma unroll
    for (int i = 0; i < 4; ++i)
      *(float4*)zq[i] = *(const float4*)&zs[(rloc + i) * LAT + k4 * 4];  // broadcast, 16B-aligned
#pragma unroll
    for (int kk = 0; kk < 4; ++kk) {
      const float4 wv = *(const float4*)&Ws[k4 * 4 + kk][cl];
#pragma unroll
      for (int i = 0; i < 4; ++i) {
        acc[i][0] = fmaf(zq[i][kk], wv.x, acc[i][0]);
        acc[i][1] = fmaf(zq[i][kk], wv.y, acc[i][1]);
        acc[i][2] = fmaf(zq[i][kk], wv.z, acc[i][2]);
        acc[i][3] = fmaf(zq[i][kk], wv.w, acc[i][3]);
      }
    }
  }

  if (c0 + cl >= DIN) return;
  const float4 db4 = *(const float4*)&db[c0 + cl];
  const float4 g4  = *(const float4*)&g3[c0 + cl];
  const float4 bb4 = *(const float4*)&bb3[c0 + cl];
#pragma unroll
  for (int i = 0; i < 4; ++i) {
    float4 v;
    v.x = elu1((acc[i][0] + db4.x) * (g4.x * BN_RS) + bb4.x);
    v.y = elu1((acc[i][1] + db4.y) * (g4.y * BN_RS) + bb4.y);
    v.z = elu1((acc[i][2] + db4.z) * (g4.z * BN_RS) + bb4.z);
    v.w = elu1((acc[i][3] + db4.w) * (g4.w * BN_RS) + bb4.w);
    *(float4*)&out[(size_t)(r0 + rloc + i) * DIN + c0 + cl] = v;  // coalesced
  }
}

extern "C" void kernel_launch(void* const* d_in, const int* in_sizes, int n_in,
                              void* d_out, int out_size, void* d_ws, size_t ws_size,
                              hipStream_t stream) {
  const float* x    = (const float*)d_in[0];
  const float* vals = (const float*)d_in[1];
  const float* W1   = (const float*)d_in[2];
  const float* b1   = (const float*)d_in[3];
  const float* g1   = (const float*)d_in[4];
  const float* bb1  = (const float*)d_in[5];
  const float* W2   = (const float*)d_in[6];
  const float* b2   = (const float*)d_in[7];
  const float* g2   = (const float*)d_in[8];
  const float* bb2  = (const float*)d_in[9];
  const float* gc1W = (const float*)d_in[10];
  const float* gc2W = (const float*)d_in[11];
  const float* gc3W = (const float*)d_in[12];
  const float* dW   = (const float*)d_in[13];
  const float* db   = (const float*)d_in[14];
  const float* g3   = (const float*)d_in[15];
  const float* bb3  = (const float*)d_in[16];
  const float* clus = (const float*)d_in[17];
  const int* erow   = (const int*)d_in[18];
  const int* ecol   = (const int*)d_in[19];

  float* out  = (float*)d_out;
  float* z_o  = out;
  float* mu_o = out + (size_t)NROWS * 28;
  float* lv_o = out + (size_t)NROWS * 36;
  float* de_o = out + (size_t)NROWS * 44;
  float* q_o  = out + (size_t)NROWS * 3044;
  float* fx_o = out + (size_t)NROWS * 3054;
  float* gz_o = out + (size_t)NROWS * 3074;

  // scratch lives inside the de_feat region (written last, fully overwritten)
  float* feat1 = de_o;
  float* t1    = de_o + (size_t)NROWS * 100;
  float* h1    = de_o + (size_t)NROWS * 132;
  float* mp    = de_o + (size_t)NROWS * 164;
  float* lp    = de_o + (size_t)NROWS * 172;

  k_gemm1<<<dim3((NROWS + 63) / 64), 256, 0, stream>>>(x, W1, b1, g1, bb1, feat1);
  k_enc2_gc1<<<dim3((NROWS + 255) / 256), 256, 0, stream>>>(feat1, W2, b2, g2, bb2, gc1W, fx_o, t1);
  k_zero<<<dim3(512), 256, 0, stream>>>(h1, NROWS * 48);          // h1 + mp + lp (contiguous)
  k_zero<<<dim3(128), 256, 0, stream>>>(mu_o, NROWS * 16);        // mu + logvar (contiguous)
  k_spmm1<<<dim3(NEDGE * 8 / 256), 256, 0, stream>>>(vals, erow, ecol, t1, h1);
  k_h1gc<<<dim3((NROWS + 255) / 256), 256, 0, stream>>>(h1, gc2W, gc3W, mp, lp);
  k_spmm2<<<dim3(NEDGE * 4 / 256), 256, 0, stream>>>(vals, erow, ecol, mp, lp, mu_o, lv_o);
  k_zq<<<dim3((NROWS + 255) / 256), 256, 0, stream>>>(fx_o, mu_o, clus, z_o, gz_o, q_o);
  k_dec<<<dim3(12, 3125), 256, 0, stream>>>(z_o, dW, db, g3, bb3, de_o);
}

// Round 3
// 1163.359 us; speedup vs baseline: 2.6605x; 1.2934x over previous
//
#include <hip/hip_runtime.h>
#include <math.h>

#define NROWS 50000
#define DIN   3000
#define FH1   100
#define FH2   20
#define GH1   32
#define GH2   8
#define KCL   10
#define LAT   28
#define NEDGE 800000

static __device__ __forceinline__ float elu1(float v) {
  return v > 0.f ? v : (__expf(v) - 1.f);
}

static __device__ __forceinline__ unsigned short f2bf(float f) {
  unsigned int u = __float_as_uint(f);
  unsigned int r = (u + 0x7FFFu + ((u >> 16) & 1u)) >> 16;
  return (unsigned short)r;
}

#define BN_RS 0.99995000374968754f  /* 1/sqrt(1+1e-4) */

typedef __attribute__((ext_vector_type(8))) short bf16x8_t;
typedef __attribute__((ext_vector_type(4))) float f32x4_t;

// ---------------- prep: Wt[n][k] = bf16(W1[k][n]), n<112 (pad0), k<3008 (pad0) ----------------
__global__ __launch_bounds__(256) void k_prepW(const float* __restrict__ W,
                                               unsigned short* __restrict__ Wt) {
  const int idx = blockIdx.x * 256 + threadIdx.x;   // 112*376 = 42112 chunks of 8
  const int n = idx / 376;
  const int kc = (idx - n * 376) * 8;
  if (n >= 112) return;
  unsigned short v[8];
#pragma unroll
  for (int j = 0; j < 8; ++j) {
    const int k = kc + j;
    const float f = (n < FH1 && k < DIN) ? W[(size_t)k * FH1 + n] : 0.f;
    v[j] = f2bf(f);
  }
  uint4 pv;
  pv.x = (unsigned)v[0] | ((unsigned)v[1] << 16);
  pv.y = (unsigned)v[2] | ((unsigned)v[3] << 16);
  pv.z = (unsigned)v[4] | ((unsigned)v[5] << 16);
  pv.w = (unsigned)v[6] | ((unsigned)v[7] << 16);
  *(uint4*)&Wt[(size_t)n * 3008 + kc] = pv;
}

// ---------------- GEMM1 via MFMA: feat1 = ELU(BN(x @ W1 + b1)) ----------------
// BM=64 (4 waves x 16 rows), N=112 (7 frags, covers 100), K-step 32, 94 steps.
// As[64][72] bf16 (stride-72 rows -> 2-way bank alias = free), Bs[112][72].
__global__ __launch_bounds__(256) void k_gemm1(
    const float* __restrict__ x, const unsigned short* __restrict__ Wt,
    const float* __restrict__ b1, const float* __restrict__ g1, const float* __restrict__ bb1,
    float* __restrict__ out)
{
  __shared__ unsigned short As[64 * 72];
  __shared__ unsigned short Bs[112 * 72];

  const int tid = threadIdx.x;
  const int w = tid >> 6, lane = tid & 63;
  const int rowBase = blockIdx.x * 64;

  // A staging: thread -> (row, 8-elem chunk)
  const int ar = tid >> 2;            // 0..63
  const int ac = (tid & 3) * 8;       // 0,8,16,24
  const bool arOK = (rowBase + ar) < NROWS;
  const float* xrow = x + (size_t)(rowBase + ar) * DIN;

  // B staging: thread<224 -> (col n, 16-elem half)
  const int bn = tid >> 1;            // 0..127 (use <112)
  const int bs = (tid & 1) * 16;      // 0,16

  f32x4_t acc[7];
#pragma unroll
  for (int f = 0; f < 7; ++f) acc[f] = (f32x4_t){0.f, 0.f, 0.f, 0.f};

  const int fr = lane & 15;
  const int fk = (lane >> 4) * 8;     // k-slice base

  for (int ks = 0; ks < 94; ++ks) {
    const int k0 = ks * 32;
    // ---- load A (8 floats), convert to bf16 ----
    float xv[8];
    if (arOK && ks != 93) {
      const float4 v0 = *(const float4*)&xrow[k0 + ac];
      const float4 v1 = *(const float4*)&xrow[k0 + ac + 4];
      xv[0]=v0.x; xv[1]=v0.y; xv[2]=v0.z; xv[3]=v0.w;
      xv[4]=v1.x; xv[5]=v1.y; xv[6]=v1.z; xv[7]=v1.w;
    } else {
#pragma unroll
      for (int j = 0; j < 8; ++j) {
        const int k = k0 + ac + j;
        xv[j] = (arOK && k < DIN) ? xrow[k] : 0.f;
      }
    }
    uint4 av;
    av.x = (unsigned)f2bf(xv[0]) | ((unsigned)f2bf(xv[1]) << 16);
    av.y = (unsigned)f2bf(xv[2]) | ((unsigned)f2bf(xv[3]) << 16);
    av.z = (unsigned)f2bf(xv[4]) | ((unsigned)f2bf(xv[5]) << 16);
    av.w = (unsigned)f2bf(xv[6]) | ((unsigned)f2bf(xv[7]) << 16);
    // ---- load B (16 bf16 = 32 B) from Wt ----
    uint4 bv0, bv1;
    if (bn < 112) {
      bv0 = *(const uint4*)&Wt[(size_t)bn * 3008 + k0 + bs];
      bv1 = *(const uint4*)&Wt[(size_t)bn * 3008 + k0 + bs + 8];
    }

    __syncthreads();   // previous iteration's reads done
    *(uint4*)&As[ar * 72 + ac] = av;
    if (bn < 112) {
      *(uint4*)&Bs[bn * 72 + bs] = bv0;
      *(uint4*)&Bs[bn * 72 + bs + 8] = bv1;
    }
    __syncthreads();

    const bf16x8_t a = *(const bf16x8_t*)&As[(w * 16 + fr) * 72 + fk];
#pragma unroll
    for (int f = 0; f < 7; ++f) {
      const bf16x8_t b = *(const bf16x8_t*)&Bs[(f * 16 + fr) * 72 + fk];
      acc[f] = __builtin_amdgcn_mfma_f32_16x16x32_bf16(a, b, acc[f], 0, 0, 0);
    }
  }

  // epilogue: C/D layout col=lane&15, row=(lane>>4)*4+reg
  const int s4 = (lane >> 4) * 4;
#pragma unroll
  for (int f = 0; f < 7; ++f) {
    const int col = f * 16 + fr;
    if (col < FH1) {
      const float sc = g1[col] * BN_RS;
      const float bbv = bb1[col];
      const float bv = b1[col];
#pragma unroll
      for (int j = 0; j < 4; ++j) {
        const int row = rowBase + w * 16 + s4 + j;
        if (row < NROWS)
          out[(size_t)row * FH1 + col] = elu1((acc[f][j] + bv) * sc + bbv);
      }
    }
  }
}

// ---------------- feat_x = ELU(BN(feat1 @ W2 + b2)); t1 = feat_x @ gc1_W ----------------
__global__ __launch_bounds__(256) void k_enc2_gc1(
    const float* __restrict__ feat1, const float* __restrict__ W2, const float* __restrict__ b2,
    const float* __restrict__ g2, const float* __restrict__ bb2,
    const float* __restrict__ gc1W,
    float* __restrict__ fx_out, float* __restrict__ t1_out)
{
  const int row = blockIdx.x * blockDim.x + threadIdx.x;
  if (row >= NROWS) return;
  float f1[FH1];
  const float4* fr = (const float4*)(feat1 + (size_t)row * FH1);
#pragma unroll
  for (int i = 0; i < FH1/4; ++i) ((float4*)f1)[i] = fr[i];

  float fx[FH2];
#pragma unroll
  for (int j = 0; j < FH2; ++j) fx[j] = b2[j];
#pragma unroll
  for (int k = 0; k < FH1; ++k) {
    const float f = f1[k];
#pragma unroll
    for (int j = 0; j < FH2; ++j) fx[j] = fmaf(f, W2[k*FH2 + j], fx[j]);
  }
#pragma unroll
  for (int j = 0; j < FH2; ++j) fx[j] = elu1(fx[j] * (g2[j] * BN_RS) + bb2[j]);

  float4* fo = (float4*)(fx_out + (size_t)row * FH2);
#pragma unroll
  for (int i = 0; i < FH2/4; ++i) fo[i] = ((float4*)fx)[i];

  float t[GH1];
#pragma unroll
  for (int j = 0; j < GH1; ++j) t[j] = 0.f;
#pragma unroll
  for (int k = 0; k < FH2; ++k) {
    const float f = fx[k];
#pragma unroll
    for (int j = 0; j < GH1; ++j) t[j] = fmaf(f, gc1W[k*GH1 + j], t[j]);
  }
  float4* to = (float4*)(t1_out + (size_t)row * GH1);
#pragma unroll
  for (int i = 0; i < GH1/4; ++i) to[i] = ((float4*)t)[i];
}

// ---------------- zero fill ----------------
__global__ void k_zero(float* __restrict__ p, int n) {
  for (int i = blockIdx.x * blockDim.x + threadIdx.x; i < n; i += gridDim.x * blockDim.x)
    p[i] = 0.f;
}

// ---------------- spmm1: h1 += val * t1[col]  (scatter to row), 8 threads/edge ----------------
__global__ void k_spmm1(const float* __restrict__ vals, const int* __restrict__ er,
                        const int* __restrict__ ec, const float* __restrict__ t1,
                        float* __restrict__ h1)
{
  const int idx = blockIdx.x * blockDim.x + threadIdx.x;
  const int e = idx >> 3, p = idx & 7;
  if (e >= NEDGE) return;
  const int r = er[e], c = ec[e];
  const float v = vals[e];
  const float4 tv = *(const float4*)&t1[(size_t)c * GH1 + p * 4];
  float* dst = &h1[(size_t)r * GH1 + p * 4];
  unsafeAtomicAdd(dst + 0, v * tv.x);
  unsafeAtomicAdd(dst + 1, v * tv.y);
  unsafeAtomicAdd(dst + 2, v * tv.z);
  unsafeAtomicAdd(dst + 3, v * tv.w);
}

// ---------------- mu_pre/lv_pre = relu(h1) @ gc2W / gc3W ----------------
__global__ __launch_bounds__(256) void k_h1gc(
    const float* __restrict__ h1, const float* __restrict__ gc2W, const float* __restrict__ gc3W,
    float* __restrict__ mp, float* __restrict__ lp)
{
  const int row = blockIdx.x * blockDim.x + threadIdx.x;
  if (row >= NROWS) return;
  float h[GH1];
  const float4* hr = (const float4*)(h1 + (size_t)row * GH1);
#pragma unroll
  for (int i = 0; i < GH1/4; ++i) ((float4*)h)[i] = hr[i];
#pragma unroll
  for (int k = 0; k < GH1; ++k) h[k] = fmaxf(h[k], 0.f);

  float m[GH2], l[GH2];
#pragma unroll
  for (int j = 0; j < GH2; ++j) { m[j] = 0.f; l[j] = 0.f; }
#pragma unroll
  for (int k = 0; k < GH1; ++k) {
    const float hv = h[k];
#pragma unroll
    for (int j = 0; j < GH2; ++j) {
      m[j] = fmaf(hv, gc2W[k*GH2 + j], m[j]);
      l[j] = fmaf(hv, gc3W[k*GH2 + j], l[j]);
    }
  }
  float4* mo = (float4*)(mp + (size_t)row * GH2);
  float4* lo = (float4*)(lp + (size_t)row * GH2);
  mo[0] = ((float4*)m)[0]; mo[1] = ((float4*)m)[1];
  lo[0] = ((float4*)l)[0]; lo[1] = ((float4*)l)[1];
}

// ---------------- spmm2: mu += val*mp[col]; lv += val*lp[col]; 4 threads/edge ----------------
__global__ void k_spmm2(const float* __restrict__ vals, const int* __restrict__ er,
                        const int* __restrict__ ec, const float* __restrict__ mp,
                        const float* __restrict__ lp,
                        float* __restrict__ mu, float* __restrict__ lv)
{
  const int idx = blockIdx.x * blockDim.x + threadIdx.x;
  const int e = idx >> 2, p = idx & 3;
  if (e >= NEDGE) return;
  const int r = er[e], c = ec[e];
  const float v = vals[e];
  const float* src = (p < 2) ? mp : lp;
  float* dstb = (p < 2) ? mu : lv;
  const int off = (p & 1) * 4;
  const float4 sv = *(const float4*)&src[(size_t)c * GH2 + off];
  float* dst = &dstb[(size_t)r * GH2 + off];
  unsafeAtomicAdd(dst + 0, v * sv.x);
  unsafeAtomicAdd(dst + 1, v * sv.y);
  unsafeAtomicAdd(dst + 2, v * sv.z);
  unsafeAtomicAdd(dst + 3, v * sv.w);
}

// ---------------- z = [feat_x | mu]; gnn_z = mu; q = student-t ----------------
__global__ __launch_bounds__(256) void k_zq(
    const float* __restrict__ fx, const float* __restrict__ mu, const float* __restrict__ clus,
    float* __restrict__ z_o, float* __restrict__ gz_o, float* __restrict__ q_o)
{
  const int row = blockIdx.x * blockDim.x + threadIdx.x;
  if (row >= NROWS) return;
  float z[LAT];
  const float4* f4 = (const float4*)(fx + (size_t)row * FH2);
#pragma unroll
  for (int i = 0; i < FH2/4; ++i) ((float4*)z)[i] = f4[i];
  const float4* m4 = (const float4*)(mu + (size_t)row * GH2);
  ((float4*)z)[5] = m4[0];
  ((float4*)z)[6] = m4[1];

  float4* zo = (float4*)(z_o + (size_t)row * LAT);
#pragma unroll
  for (int i = 0; i < LAT/4; ++i) zo[i] = ((float4*)z)[i];
  float4* go = (float4*)(gz_o + (size_t)row * GH2);
  go[0] = m4[0]; go[1] = m4[1];

  float q[KCL];
  float ssum = 0.f;
#pragma unroll
  for (int j = 0; j < KCL; ++j) {
    float d = 0.f;
#pragma unroll
    for (int k = 0; k < LAT; ++k) {
      const float df = z[k] - clus[j*LAT + k];
      d = fmaf(df, df, d);
    }
    q[j] = 1.f / (1.f + d);
    ssum += q[j];
  }
  const float inv = 1.f / ssum;
#pragma unroll
  for (int j = 0; j < KCL; ++j) q[j] *= inv;
  float2* qo = (float2*)(q_o + (size_t)row * KCL);
#pragma unroll
  for (int i = 0; i < KCL/2; ++i) qo[i] = ((float2*)q)[i];
}

// ---------------- decoder: 16 rows x 256 cols per block, LDS-staged ----------------
__global__ __launch_bounds__(256) void k_dec(
    const float* __restrict__ z, const float* __restrict__ W, const float* __restrict__ db,
    const float* __restrict__ g3, const float* __restrict__ bb3, float* __restrict__ out)
{
  __shared__ float Ws[LAT][256];   // 28 KB
  __shared__ float zs[16 * LAT];   // 1.75 KB

  const int tid = threadIdx.x;
  const int c0  = blockIdx.x * 256;
  const int r0  = blockIdx.y * 16;

#pragma unroll
  for (int rep = 0; rep < 7; ++rep) {
    const int f4 = rep * 256 + tid;
    const int k  = f4 >> 6;
    const int cg = (f4 & 63) * 4;
    float4 v = make_float4(0.f, 0.f, 0.f, 0.f);
    if (c0 + cg < DIN) v = *(const float4*)&W[(size_t)k * DIN + c0 + cg];
    *(float4*)&Ws[k][cg] = v;
  }
  if (tid < 112) {
    *(float4*)&zs[tid * 4] = *(const float4*)&z[(size_t)r0 * LAT + tid * 4];
  }
  __syncthreads();

  const int w    = tid >> 6;
  const int lane = tid & 63;
  const int cl   = lane * 4;
  const int rloc = w * 4;

  float acc[4][4];
#pragma unroll
  for (int i = 0; i < 4; ++i)
#pragma unroll
    for (int j = 0; j < 4; ++j) acc[i][j] = 0.f;

#pragma unroll
  for (int k4 = 0; k4 < 7; ++k4) {
    float zq[4][4];
#pragma unroll
    for (int i = 0; i < 4; ++i)
      *(float4*)zq[i] = *(const float4*)&zs[(rloc + i) * LAT + k4 * 4];
#pragma unroll
    for (int kk = 0; kk < 4; ++kk) {
      const float4 wv = *(const float4*)&Ws[k4 * 4 + kk][cl];
#pragma unroll
      for (int i = 0; i < 4; ++i) {
        acc[i][0] = fmaf(zq[i][kk], wv.x, acc[i][0]);
        acc[i][1] = fmaf(zq[i][kk], wv.y, acc[i][1]);
        acc[i][2] = fmaf(zq[i][kk], wv.z, acc[i][2]);
        acc[i][3] = fmaf(zq[i][kk], wv.w, acc[i][3]);
      }
    }
  }

  if (c0 + cl >= DIN) return;
  const float4 db4 = *(const float4*)&db[c0 + cl];
  const float4 g4  = *(const float4*)&g3[c0 + cl];
  const float4 bb4 = *(const float4*)&bb3[c0 + cl];
#pragma unroll
  for (int i = 0; i < 4; ++i) {
    float4 v;
    v.x = elu1((acc[i][0] + db4.x) * (g4.x * BN_RS) + bb4.x);
    v.y = elu1((acc[i][1] + db4.y) * (g4.y * BN_RS) + bb4.y);
    v.z = elu1((acc[i][2] + db4.z) * (g4.z * BN_RS) + bb4.z);
    v.w = elu1((acc[i][3] + db4.w) * (g4.w * BN_RS) + bb4.w);
    *(float4*)&out[(size_t)(r0 + rloc + i) * DIN + c0 + cl] = v;
  }
}

extern "C" void kernel_launch(void* const* d_in, const int* in_sizes, int n_in,
                              void* d_out, int out_size, void* d_ws, size_t ws_size,
                              hipStream_t stream) {
  const float* x    = (const float*)d_in[0];
  const float* vals = (const float*)d_in[1];
  const float* W1   = (const float*)d_in[2];
  const float* b1   = (const float*)d_in[3];
  const float* g1   = (const float*)d_in[4];
  const float* bb1  = (const float*)d_in[5];
  const float* W2   = (const float*)d_in[6];
  const float* b2   = (const float*)d_in[7];
  const float* g2   = (const float*)d_in[8];
  const float* bb2  = (const float*)d_in[9];
  const float* gc1W = (const float*)d_in[10];
  const float* gc2W = (const float*)d_in[11];
  const float* gc3W = (const float*)d_in[12];
  const float* dW   = (const float*)d_in[13];
  const float* db   = (const float*)d_in[14];
  const float* g3   = (const float*)d_in[15];
  const float* bb3  = (const float*)d_in[16];
  const float* clus = (const float*)d_in[17];
  const int* erow   = (const int*)d_in[18];
  const int* ecol   = (const int*)d_in[19];

  float* out  = (float*)d_out;
  float* z_o  = out;
  float* mu_o = out + (size_t)NROWS * 28;
  float* lv_o = out + (size_t)NROWS * 36;
  float* de_o = out + (size_t)NROWS * 44;
  float* q_o  = out + (size_t)NROWS * 3044;
  float* fx_o = out + (size_t)NROWS * 3054;
  float* gz_o = out + (size_t)NROWS * 3074;

  // scratch lives inside the de_feat region (written last, fully overwritten)
  float* feat1 = de_o;
  float* t1    = de_o + (size_t)NROWS * 100;
  float* h1    = de_o + (size_t)NROWS * 132;
  float* mp    = de_o + (size_t)NROWS * 164;
  float* lp    = de_o + (size_t)NROWS * 172;
  unsigned short* Wt = (unsigned short*)(de_o + (size_t)NROWS * 200);  // 112x3008 bf16

  k_prepW<<<dim3(165), 256, 0, stream>>>(W1, Wt);
  k_gemm1<<<dim3(782), 256, 0, stream>>>(x, Wt, b1, g1, bb1, feat1);
  k_enc2_gc1<<<dim3((NROWS + 255) / 256), 256, 0, stream>>>(feat1, W2, b2, g2, bb2, gc1W, fx_o, t1);
  k_zero<<<dim3(512), 256, 0, stream>>>(h1, NROWS * 48);
  k_zero<<<dim3(128), 256, 0, stream>>>(mu_o, NROWS * 16);
  k_spmm1<<<dim3(NEDGE * 8 / 256), 256, 0, stream>>>(vals, erow, ecol, t1, h1);
  k_h1gc<<<dim3((NROWS + 255) / 256), 256, 0, stream>>>(h1, gc2W, gc3W, mp, lp);
  k_spmm2<<<dim3(NEDGE * 4 / 256), 256, 0, stream>>>(vals, erow, ecol, mp, lp, mu_o, lv_o);
  k_zq<<<dim3((NROWS + 255) / 256), 256, 0, stream>>>(fx_o, mu_o, clus, z_o, gz_o, q_o);
  k_dec<<<dim3(12, 3125), 256, 0, stream>>>(z_o, dW, db, g3, bb3, de_o);
}

// Round 4
// 854.974 us; speedup vs baseline: 3.6201x; 1.3607x over previous
//
#include <hip/hip_runtime.h>
#include <math.h>

#define NROWS 50000
#define DIN   3000
#define FH1   100
#define FH2   20
#define GH1   32
#define GH2   8
#define KCL   10
#define LAT   28
#define NEDGE 800000

static __device__ __forceinline__ float elu1(float v) {
  return v > 0.f ? v : (__expf(v) - 1.f);
}

static __device__ __forceinline__ unsigned short f2bf(float f) {
  unsigned int u = __float_as_uint(f);
  unsigned int r = (u + 0x7FFFu + ((u >> 16) & 1u)) >> 16;
  return (unsigned short)r;
}

#define BN_RS 0.99995000374968754f  /* 1/sqrt(1+1e-4) */

typedef __attribute__((ext_vector_type(8))) short bf16x8_t;
typedef __attribute__((ext_vector_type(4))) float f32x4_t;

// ---------------- prep: Wt[n][k] = bf16(W1[k][n]), n<112 (pad0), k<3008 (pad0) ----------------
__global__ __launch_bounds__(256) void k_prepW(const float* __restrict__ W,
                                               unsigned short* __restrict__ Wt) {
  const int idx = blockIdx.x * 256 + threadIdx.x;   // 112*376 chunks of 8
  const int n = idx / 376;
  const int kc = (idx - n * 376) * 8;
  if (n >= 112) return;
  unsigned short v[8];
#pragma unroll
  for (int j = 0; j < 8; ++j) {
    const int k = kc + j;
    const float f = (n < FH1 && k < DIN) ? W[(size_t)k * FH1 + n] : 0.f;
    v[j] = f2bf(f);
  }
  uint4 pv;
  pv.x = (unsigned)v[0] | ((unsigned)v[1] << 16);
  pv.y = (unsigned)v[2] | ((unsigned)v[3] << 16);
  pv.z = (unsigned)v[4] | ((unsigned)v[5] << 16);
  pv.w = (unsigned)v[6] | ((unsigned)v[7] << 16);
  *(uint4*)&Wt[(size_t)n * 3008 + kc] = pv;
}

// ---------------- GEMM1 v3: LDS-free MFMA. feat1 = ELU(BN(x @ W1 + b1)) ----------------
// Per-lane direct fragment loads: A row = lane&15 (32B contiguous fp32 from x),
// B col = f*16 + (lane&15) from Wt (16B bf16, L2-resident). No LDS, no barriers.
__global__ __launch_bounds__(256) void k_gemm1(
    const float* __restrict__ x, const unsigned short* __restrict__ Wt,
    const float* __restrict__ b1, const float* __restrict__ g1, const float* __restrict__ bb1,
    float* __restrict__ out)
{
  const int tid = threadIdx.x;
  const int w = tid >> 6, lane = tid & 63;
  const int fr = lane & 15;
  const int fk = (lane >> 4) * 8;          // k-slice base 0,8,16,24
  const int rowBase = blockIdx.x * 64;

  const int myRow = rowBase + w * 16 + fr;
  const int rowc = myRow < NROWS ? myRow : (NROWS - 1);   // clamp: keep address legal
  const float* xrow = x + (size_t)rowc * DIN;

  f32x4_t acc[7];
#pragma unroll
  for (int f = 0; f < 7; ++f) acc[f] = (f32x4_t){0.f, 0.f, 0.f, 0.f};

  for (int ks = 0; ks < 94; ++ks) {
    const int k0 = ks * 32;
    // ---- A fragment: 8 contiguous fp32 -> bf16x8 ----
    float4 v0 = make_float4(0.f,0.f,0.f,0.f), v1 = v0;
    if (ks != 93 || fk <= 16) {            // ks=93,fk=24 -> fully OOB (k>=3000) -> zeros
      v0 = *(const float4*)&xrow[k0 + fk];
      v1 = *(const float4*)&xrow[k0 + fk + 4];
    }
    uint4 av;
    av.x = (unsigned)f2bf(v0.x) | ((unsigned)f2bf(v0.y) << 16);
    av.y = (unsigned)f2bf(v0.z) | ((unsigned)f2bf(v0.w) << 16);
    av.z = (unsigned)f2bf(v1.x) | ((unsigned)f2bf(v1.y) << 16);
    av.w = (unsigned)f2bf(v1.z) | ((unsigned)f2bf(v1.w) << 16);
    const bf16x8_t a = *(const bf16x8_t*)&av;
    // ---- B fragments: 16B each from Wt, L2-hit ----
#pragma unroll
    for (int f = 0; f < 7; ++f) {
      const uint4 bv = *(const uint4*)&Wt[(size_t)(f * 16 + fr) * 3008 + k0 + fk];
      acc[f] = __builtin_amdgcn_mfma_f32_16x16x32_bf16(a, *(const bf16x8_t*)&bv, acc[f], 0, 0, 0);
    }
  }

  // epilogue: C/D layout col=lane&15, row=(lane>>4)*4+reg
  const int s4 = (lane >> 4) * 4;
#pragma unroll
  for (int f = 0; f < 7; ++f) {
    const int col = f * 16 + fr;
    if (col < FH1) {
      const float sc = g1[col] * BN_RS;
      const float bbv = bb1[col];
      const float bv = b1[col];
#pragma unroll
      for (int j = 0; j < 4; ++j) {
        const int row = rowBase + w * 16 + s4 + j;
        if (row < NROWS)
          out[(size_t)row * FH1 + col] = elu1((acc[f][j] + bv) * sc + bbv);
      }
    }
  }
}

// ---------------- feat_x = ELU(BN(feat1 @ W2 + b2)); t1 = feat_x @ gc1_W ----------------
__global__ __launch_bounds__(256) void k_enc2_gc1(
    const float* __restrict__ feat1, const float* __restrict__ W2, const float* __restrict__ b2,
    const float* __restrict__ g2, const float* __restrict__ bb2,
    const float* __restrict__ gc1W,
    float* __restrict__ fx_out, float* __restrict__ t1_out)
{
  const int row = blockIdx.x * blockDim.x + threadIdx.x;
  if (row >= NROWS) return;
  float f1[FH1];
  const float4* fr = (const float4*)(feat1 + (size_t)row * FH1);
#pragma unroll
  for (int i = 0; i < FH1/4; ++i) ((float4*)f1)[i] = fr[i];

  float fx[FH2];
#pragma unroll
  for (int j = 0; j < FH2; ++j) fx[j] = b2[j];
#pragma unroll
  for (int k = 0; k < FH1; ++k) {
    const float f = f1[k];
#pragma unroll
    for (int j = 0; j < FH2; ++j) fx[j] = fmaf(f, W2[k*FH2 + j], fx[j]);
  }
#pragma unroll
  for (int j = 0; j < FH2; ++j) fx[j] = elu1(fx[j] * (g2[j] * BN_RS) + bb2[j]);

  float4* fo = (float4*)(fx_out + (size_t)row * FH2);
#pragma unroll
  for (int i = 0; i < FH2/4; ++i) fo[i] = ((float4*)fx)[i];

  float t[GH1];
#pragma unroll
  for (int j = 0; j < GH1; ++j) t[j] = 0.f;
#pragma unroll
  for (int k = 0; k < FH2; ++k) {
    const float f = fx[k];
#pragma unroll
    for (int j = 0; j < GH1; ++j) t[j] = fmaf(f, gc1W[k*GH1 + j], t[j]);
  }
  float4* to = (float4*)(t1_out + (size_t)row * GH1);
#pragma unroll
  for (int i = 0; i < GH1/4; ++i) to[i] = ((float4*)t)[i];
}

// ---------------- CSR build: zero -> hist -> scan -> scatter ----------------
__global__ void k_zero_i(int* __restrict__ p, int n) {
  for (int i = blockIdx.x * blockDim.x + threadIdx.x; i < n; i += gridDim.x * blockDim.x)
    p[i] = 0;
}

__global__ void k_hist(const int* __restrict__ er, int* __restrict__ deg) {
  const int e = blockIdx.x * 256 + threadIdx.x;
  if (e < NEDGE) atomicAdd(&deg[er[e]], 1);
}

__global__ __launch_bounds__(1024) void k_scan(const int* __restrict__ deg,
                                               int* __restrict__ start) {
  __shared__ int sm[1024];
  const int t = threadIdx.x;
  const int c0 = t * 49;
  const int c1 = (c0 + 49 < NROWS) ? c0 + 49 : NROWS;
  int s = 0;
  for (int i = c0; i < c1; ++i) s += deg[i];
  sm[t] = s;
  __syncthreads();
  for (int off = 1; off < 1024; off <<= 1) {
    int v = (t >= off) ? sm[t - off] : 0;
    __syncthreads();
    sm[t] += v;
    __syncthreads();
  }
  int run = (t == 0) ? 0 : sm[t - 1];
  for (int i = c0; i < c1; ++i) { start[i] = run; run += deg[i]; }
  if (t == 0) start[NROWS] = NEDGE;
}

__global__ void k_scatter(const int* __restrict__ er, const int* __restrict__ ec,
                          const float* __restrict__ vals, const int* __restrict__ start,
                          int* __restrict__ cnt, int* __restrict__ colS,
                          float* __restrict__ valS) {
  const int e = blockIdx.x * 256 + threadIdx.x;
  if (e >= NEDGE) return;
  const int r = er[e];
  const int pos = start[r] + atomicAdd(&cnt[r], 1);
  colS[pos] = ec[e];
  valS[pos] = vals[e];
}

// ---------------- spmm1 gather: h1[r] = sum_j val*t1[col], 8 thr/row ----------------
__global__ __launch_bounds__(256) void k_spmm1g(
    const int* __restrict__ start, const int* __restrict__ colS, const float* __restrict__ valS,
    const float* __restrict__ t1, float* __restrict__ h1)
{
  const int tid = threadIdx.x;
  const int row = blockIdx.x * 32 + (tid >> 3);
  const int p = tid & 7;
  if (row >= NROWS) return;
  const int s = start[row], e = start[row + 1];
  float4 acc = make_float4(0.f, 0.f, 0.f, 0.f);
  for (int j = s; j < e; ++j) {
    const int c = colS[j];
    const float v = valS[j];
    const float4 tv = *(const float4*)&t1[(size_t)c * GH1 + p * 4];
    acc.x = fmaf(v, tv.x, acc.x);
    acc.y = fmaf(v, tv.y, acc.y);
    acc.z = fmaf(v, tv.z, acc.z);
    acc.w = fmaf(v, tv.w, acc.w);
  }
  *(float4*)&h1[(size_t)row * GH1 + p * 4] = acc;
}

// ---------------- mu_pre/lv_pre = relu(h1) @ gc2W / gc3W ----------------
__global__ __launch_bounds__(256) void k_h1gc(
    const float* __restrict__ h1, const float* __restrict__ gc2W, const float* __restrict__ gc3W,
    float* __restrict__ mp, float* __restrict__ lp)
{
  const int row = blockIdx.x * blockDim.x + threadIdx.x;
  if (row >= NROWS) return;
  float h[GH1];
  const float4* hr = (const float4*)(h1 + (size_t)row * GH1);
#pragma unroll
  for (int i = 0; i < GH1/4; ++i) ((float4*)h)[i] = hr[i];
#pragma unroll
  for (int k = 0; k < GH1; ++k) h[k] = fmaxf(h[k], 0.f);

  float m[GH2], l[GH2];
#pragma unroll
  for (int j = 0; j < GH2; ++j) { m[j] = 0.f; l[j] = 0.f; }
#pragma unroll
  for (int k = 0; k < GH1; ++k) {
    const float hv = h[k];
#pragma unroll
    for (int j = 0; j < GH2; ++j) {
      m[j] = fmaf(hv, gc2W[k*GH2 + j], m[j]);
      l[j] = fmaf(hv, gc3W[k*GH2 + j], l[j]);
    }
  }
  float4* mo = (float4*)(mp + (size_t)row * GH2);
  float4* lo = (float4*)(lp + (size_t)row * GH2);
  mo[0] = ((float4*)m)[0]; mo[1] = ((float4*)m)[1];
  lo[0] = ((float4*)l)[0]; lo[1] = ((float4*)l)[1];
}

// ---------------- spmm2 gather: mu/lv, 4 thr/row ----------------
__global__ __launch_bounds__(256) void k_spmm2g(
    const int* __restrict__ start, const int* __restrict__ colS, const float* __restrict__ valS,
    const float* __restrict__ mp, const float* __restrict__ lp,
    float* __restrict__ mu, float* __restrict__ lv)
{
  const int tid = threadIdx.x;
  const int row = blockIdx.x * 64 + (tid >> 2);
  const int p = tid & 3;
  if (row >= NROWS) return;
  const float* src = (p < 2) ? mp : lp;
  float* dst = (p < 2) ? mu : lv;
  const int off = (p & 1) * 4;
  const int s = start[row], e = start[row + 1];
  float4 acc = make_float4(0.f, 0.f, 0.f, 0.f);
  for (int j = s; j < e; ++j) {
    const int c = colS[j];
    const float v = valS[j];
    const float4 sv = *(const float4*)&src[(size_t)c * GH2 + off];
    acc.x = fmaf(v, sv.x, acc.x);
    acc.y = fmaf(v, sv.y, acc.y);
    acc.z = fmaf(v, sv.z, acc.z);
    acc.w = fmaf(v, sv.w, acc.w);
  }
  *(float4*)&dst[(size_t)row * GH2 + off] = acc;
}

// ---------------- z = [feat_x | mu]; gnn_z = mu; q = student-t ----------------
__global__ __launch_bounds__(256) void k_zq(
    const float* __restrict__ fx, const float* __restrict__ mu, const float* __restrict__ clus,
    float* __restrict__ z_o, float* __restrict__ gz_o, float* __restrict__ q_o)
{
  const int row = blockIdx.x * blockDim.x + threadIdx.x;
  if (row >= NROWS) return;
  float z[LAT];
  const float4* f4 = (const float4*)(fx + (size_t)row * FH2);
#pragma unroll
  for (int i = 0; i < FH2/4; ++i) ((float4*)z)[i] = f4[i];
  const float4* m4 = (const float4*)(mu + (size_t)row * GH2);
  ((float4*)z)[5] = m4[0];
  ((float4*)z)[6] = m4[1];

  float4* zo = (float4*)(z_o + (size_t)row * LAT);
#pragma unroll
  for (int i = 0; i < LAT/4; ++i) zo[i] = ((float4*)z)[i];
  float4* go = (float4*)(gz_o + (size_t)row * GH2);
  go[0] = m4[0]; go[1] = m4[1];

  float q[KCL];
  float ssum = 0.f;
#pragma unroll
  for (int j = 0; j < KCL; ++j) {
    float d = 0.f;
#pragma unroll
    for (int k = 0; k < LAT; ++k) {
      const float df = z[k] - clus[j*LAT + k];
      d = fmaf(df, df, d);
    }
    q[j] = 1.f / (1.f + d);
    ssum += q[j];
  }
  const float inv = 1.f / ssum;
#pragma unroll
  for (int j = 0; j < KCL; ++j) q[j] *= inv;
  float2* qo = (float2*)(q_o + (size_t)row * KCL);
#pragma unroll
  for (int i = 0; i < KCL/2; ++i) qo[i] = ((float2*)q)[i];
}

// ---------------- decoder: 16 rows x 256 cols per block, LDS-staged ----------------
__global__ __launch_bounds__(256) void k_dec(
    const float* __restrict__ z, const float* __restrict__ W, const float* __restrict__ db,
    const float* __restrict__ g3, const float* __restrict__ bb3, float* __restrict__ out)
{
  __shared__ float Ws[LAT][256];   // 28 KB
  __shared__ float zs[16 * LAT];   // 1.75 KB

  const int tid = threadIdx.x;
  const int c0  = blockIdx.x * 256;
  const int r0  = blockIdx.y * 16;

#pragma unroll
  for (int rep = 0; rep < 7; ++rep) {
    const int f4 = rep * 256 + tid;
    const int k  = f4 >> 6;
    const int cg = (f4 & 63) * 4;
    float4 v = make_float4(0.f, 0.f, 0.f, 0.f);
    if (c0 + cg < DIN) v = *(const float4*)&W[(size_t)k * DIN + c0 + cg];
    *(float4*)&Ws[k][cg] = v;
  }
  if (tid < 112) {
    *(float4*)&zs[tid * 4] = *(const float4*)&z[(size_t)r0 * LAT + tid * 4];
  }
  __syncthreads();

  const int w    = tid >> 6;
  const int lane = tid & 63;
  const int cl   = lane * 4;
  const int rloc = w * 4;

  float acc[4][4];
#pragma unroll
  for (int i = 0; i < 4; ++i)
#pragma unroll
    for (int j = 0; j < 4; ++j) acc[i][j] = 0.f;

#pragma unroll
  for (int k4 = 0; k4 < 7; ++k4) {
    float zq[4][4];
#pragma unroll
    for (int i = 0; i < 4; ++i)
      *(float4*)zq[i] = *(const float4*)&zs[(rloc + i) * LAT + k4 * 4];
#pragma unroll
    for (int kk = 0; kk < 4; ++kk) {
      const float4 wv = *(const float4*)&Ws[k4 * 4 + kk][cl];
#pragma unroll
      for (int i = 0; i < 4; ++i) {
        acc[i][0] = fmaf(zq[i][kk], wv.x, acc[i][0]);
        acc[i][1] = fmaf(zq[i][kk], wv.y, acc[i][1]);
        acc[i][2] = fmaf(zq[i][kk], wv.z, acc[i][2]);
        acc[i][3] = fmaf(zq[i][kk], wv.w, acc[i][3]);
      }
    }
  }

  if (c0 + cl >= DIN) return;
  const float4 db4 = *(const float4*)&db[c0 + cl];
  const float4 g4  = *(const float4*)&g3[c0 + cl];
  const float4 bb4 = *(const float4*)&bb3[c0 + cl];
#pragma unroll
  for (int i = 0; i < 4; ++i) {
    float4 v;
    v.x = elu1((acc[i][0] + db4.x) * (g4.x * BN_RS) + bb4.x);
    v.y = elu1((acc[i][1] + db4.y) * (g4.y * BN_RS) + bb4.y);
    v.z = elu1((acc[i][2] + db4.z) * (g4.z * BN_RS) + bb4.z);
    v.w = elu1((acc[i][3] + db4.w) * (g4.w * BN_RS) + bb4.w);
    *(float4*)&out[(size_t)(r0 + rloc + i) * DIN + c0 + cl] = v;
  }
}

extern "C" void kernel_launch(void* const* d_in, const int* in_sizes, int n_in,
                              void* d_out, int out_size, void* d_ws, size_t ws_size,
                              hipStream_t stream) {
  const float* x    = (const float*)d_in[0];
  const float* vals = (const float*)d_in[1];
  const float* W1   = (const float*)d_in[2];
  const float* b1   = (const float*)d_in[3];
  const float* g1   = (const float*)d_in[4];
  const float* bb1  = (const float*)d_in[5];
  const float* W2   = (const float*)d_in[6];
  const float* b2   = (const float*)d_in[7];
  const float* g2   = (const float*)d_in[8];
  const float* bb2  = (const float*)d_in[9];
  const float* gc1W = (const float*)d_in[10];
  const float* gc2W = (const float*)d_in[11];
  const float* gc3W = (const float*)d_in[12];
  const float* dW   = (const float*)d_in[13];
  const float* db   = (const float*)d_in[14];
  const float* g3   = (const float*)d_in[15];
  const float* bb3  = (const float*)d_in[16];
  const float* clus = (const float*)d_in[17];
  const int* erow   = (const int*)d_in[18];
  const int* ecol   = (const int*)d_in[19];

  float* out  = (float*)d_out;
  float* z_o  = out;
  float* mu_o = out + (size_t)NROWS * 28;
  float* lv_o = out + (size_t)NROWS * 36;
  float* de_o = out + (size_t)NROWS * 44;
  float* q_o  = out + (size_t)NROWS * 3044;
  float* fx_o = out + (size_t)NROWS * 3054;
  float* gz_o = out + (size_t)NROWS * 3074;

  // scratch lives inside the de_feat region (written last, fully overwritten)
  float* feat1 = de_o;                                   // [0, 100N)
  float* t1    = de_o + (size_t)NROWS * 100;             // [100N, 132N)
  float* h1    = de_o + (size_t)NROWS * 132;             // [132N, 164N)
  float* mp    = de_o + (size_t)NROWS * 164;             // [164N, 172N)
  float* lp    = de_o + (size_t)NROWS * 172;             // [172N, 180N)
  unsigned short* Wt = (unsigned short*)(de_o + (size_t)NROWS * 200);  // 112x3008 bf16 ~ [200N, 204N)
  int*   deg   = (int*)(de_o + (size_t)NROWS * 210);     // [210N, 211N)
  int*   cnt   = (int*)(de_o + (size_t)NROWS * 211);     // [211N, 212N)
  int*   startA= (int*)(de_o + (size_t)NROWS * 212);     // [212N, 214N) (50001 ints)
  int*   colS  = (int*)(de_o + (size_t)NROWS * 214);     // [214N, 230N)
  float* valS  = de_o + (size_t)NROWS * 230;             // [230N, 246N)

  k_prepW<<<dim3(165), 256, 0, stream>>>(W1, Wt);
  k_gemm1<<<dim3(782), 256, 0, stream>>>(x, Wt, b1, g1, bb1, feat1);
  k_enc2_gc1<<<dim3((NROWS + 255) / 256), 256, 0, stream>>>(feat1, W2, b2, g2, bb2, gc1W, fx_o, t1);

  // CSR build (deg & cnt contiguous -> one zero pass)
  k_zero_i<<<dim3(128), 256, 0, stream>>>(deg, 2 * NROWS);
  k_hist<<<dim3((NEDGE + 255) / 256), 256, 0, stream>>>(erow, deg);
  k_scan<<<dim3(1), 1024, 0, stream>>>(deg, startA);
  k_scatter<<<dim3((NEDGE + 255) / 256), 256, 0, stream>>>(erow, ecol, vals, startA, cnt, colS, valS);

  k_spmm1g<<<dim3((NROWS + 31) / 32), 256, 0, stream>>>(startA, colS, valS, t1, h1);
  k_h1gc<<<dim3((NROWS + 255) / 256), 256, 0, stream>>>(h1, gc2W, gc3W, mp, lp);
  k_spmm2g<<<dim3((NROWS + 63) / 64), 256, 0, stream>>>(startA, colS, valS, mp, lp, mu_o, lv_o);
  k_zq<<<dim3((NROWS + 255) / 256), 256, 0, stream>>>(fx_o, mu_o, clus, z_o, gz_o, q_o);
  k_dec<<<dim3(12, 3125), 256, 0, stream>>>(z_o, dW, db, g3, bb3, de_o);
}